// Round 1
// baseline (1110.624 us; speedup 1.0000x reference)
//
#include <hip/hip_runtime.h>
#include <hip/hip_bf16.h>

#define H 128
#define NEG 0.01f

typedef __bf16 bf16;
typedef bf16 bf16x4 __attribute__((ext_vector_type(4)));
typedef bf16 bf16x8 __attribute__((ext_vector_type(8)));
typedef float f32x4 __attribute__((ext_vector_type(4)));

// ---------------- CSR build ----------------

__global__ void k_rdeg(const float* __restrict__ deg, float* __restrict__ rdeg, int n) {
    int i = blockIdx.x * 256 + threadIdx.x;
    if (i < n) rdeg[i] = 1.0f / deg[i];
}

__global__ void k_hist(const int* __restrict__ dst, int* __restrict__ cnt, int e) {
    int i = blockIdx.x * 256 + threadIdx.x;
    if (i < e) atomicAdd(&cnt[dst[i]], 1);
}

__global__ void k_scan1(const int* __restrict__ cnt, int* __restrict__ part, int n) {
    __shared__ int sh[256];
    int i = blockIdx.x * 256 + threadIdx.x;
    sh[threadIdx.x] = (i < n) ? cnt[i] : 0;
    __syncthreads();
    for (int off = 128; off > 0; off >>= 1) {
        if (threadIdx.x < off) sh[threadIdx.x] += sh[threadIdx.x + off];
        __syncthreads();
    }
    if (threadIdx.x == 0) part[blockIdx.x] = sh[0];
}

__global__ void k_scan2(int* part, int nblk) {
    __shared__ int sh[256];
    int t = threadIdx.x;
    sh[t] = (t < nblk) ? part[t] : 0;
    __syncthreads();
    for (int off = 1; off < 256; off <<= 1) {
        int v = (t >= off) ? sh[t - off] : 0;
        __syncthreads();
        sh[t] += v;
        __syncthreads();
    }
    if (t < nblk) part[t] = (t == 0) ? 0 : sh[t - 1];
}

__global__ void k_scan3(const int* __restrict__ cnt, const int* __restrict__ part,
                        int* __restrict__ row_ptr, int* __restrict__ nxt, int n, int e) {
    __shared__ int sh[256];
    int t = threadIdx.x;
    int i = blockIdx.x * 256 + t;
    sh[t] = (i < n) ? cnt[i] : 0;
    __syncthreads();
    for (int off = 1; off < 256; off <<= 1) {
        int v = (t >= off) ? sh[t - off] : 0;
        __syncthreads();
        sh[t] += v;
        __syncthreads();
    }
    int excl = part[blockIdx.x] + ((t == 0) ? 0 : sh[t - 1]);
    if (i < n) { row_ptr[i] = excl; nxt[i] = excl; }
    if (i == 0) row_ptr[n] = e;
}

__global__ void k_fill(const int* __restrict__ src, const int* __restrict__ dst,
                       int* __restrict__ nxt, int* __restrict__ ssrc, int e) {
    int i = blockIdx.x * 256 + threadIdx.x;
    if (i < e) {
        int p = atomicAdd(&nxt[dst[i]], 1);
        ssrc[p] = src[i];
    }
}

// ---------------- aggregation (CSR gather, no atomics) ----------------
// one wave per node (64 lanes x float2 = 128 cols), 4 nodes per block

template<bool SCALED>
__global__ void k_agg(const float* __restrict__ hin, const int* __restrict__ row_ptr,
                      const int* __restrict__ ssrc, const float* __restrict__ rdeg,
                      float* __restrict__ out, int n) {
    int v = blockIdx.x * 4 + (threadIdx.x >> 6);
    if (v >= n) return;
    int c = (threadIdx.x & 63) * 2;
    int e0 = row_ptr[v], e1 = row_ptr[v + 1];
    float a0 = 0.f, a1 = 0.f;
    for (int e = e0; e < e1; e++) {
        int s = ssrc[e];
        float2 x = *(const float2*)(hin + (size_t)s * H + c);
        if (SCALED) { float r = rdeg[s]; x.x *= r; x.y *= r; }
        a0 += x.x; a1 += x.y;
    }
    if (SCALED) {
        float2 hv = *(const float2*)(hin + (size_t)v * H + c);
        a0 += hv.x; a1 += hv.y;
    }
    float2 o; o.x = a0; o.y = a1;
    *(float2*)(out + (size_t)v * H + c) = o;
}

// ---------------- bf16 MFMA GEMM: C[M,128] = act(A[M,K] @ B[K,128] + bias) ----------------
// block: 256 threads = 4 waves, tile 64 rows x 128 cols, BK=64

template<int K, bool RELU>
__global__ __launch_bounds__(256)
void k_gemm(const float* __restrict__ A, const float* __restrict__ Bw,
            const float* __restrict__ bias, float* __restrict__ C, int M) {
    constexpr int BM = 64, BN = 128, BK = 64, LDT = BK + 8;  // +8 bf16 pad: kills LDS bank conflicts
    __shared__ alignas(16) bf16 As[BM][LDT];
    __shared__ alignas(16) bf16 Bs[BN][LDT];   // B transposed: Bs[n][k]
    const int tid = threadIdx.x;
    const int wave = tid >> 6, lane = tid & 63;
    const int blockRow = blockIdx.x * BM;

    f32x4 acc[8];
#pragma unroll
    for (int t = 0; t < 8; t++) acc[t] = (f32x4){0.f, 0.f, 0.f, 0.f};

    for (int k0 = 0; k0 < K; k0 += BK) {
        // stage A tile (fp32 -> bf16)
#pragma unroll
        for (int it = 0; it < (BM * BK / 4) / 256; it++) {
            int s = it * 256 + tid;
            int row = s >> 4, f4 = (s & 15) * 4;
            int grow = blockRow + row; if (grow > M - 1) grow = M - 1;
            const float4 v = *(const float4*)(A + (size_t)grow * K + k0 + f4);
            bf16x4 w = { (bf16)v.x, (bf16)v.y, (bf16)v.z, (bf16)v.w };
            *(bf16x4*)&As[row][f4] = w;
        }
        // stage B tile transposed (fp32 -> bf16)
#pragma unroll
        for (int it = 0; it < (BK * BN / 4) / 256; it++) {
            int s = it * 256 + tid;
            int kr = s >> 5, f4 = (s & 31) * 4;
            const float4 v = *(const float4*)(Bw + (size_t)(k0 + kr) * BN + f4);
            Bs[f4 + 0][kr] = (bf16)v.x;
            Bs[f4 + 1][kr] = (bf16)v.y;
            Bs[f4 + 2][kr] = (bf16)v.z;
            Bs[f4 + 3][kr] = (bf16)v.w;
        }
        __syncthreads();
#pragma unroll
        for (int kk = 0; kk < BK; kk += 32) {
            bf16x8 af = *(const bf16x8*)&As[wave * 16 + (lane & 15)][kk + (lane >> 4) * 8];
#pragma unroll
            for (int t = 0; t < 8; t++) {
                bf16x8 bf = *(const bf16x8*)&Bs[t * 16 + (lane & 15)][kk + (lane >> 4) * 8];
                acc[t] = __builtin_amdgcn_mfma_f32_16x16x32_bf16(af, bf, acc[t], 0, 0, 0);
            }
        }
        __syncthreads();
    }
    // epilogue: D[row=(lane>>4)*4+reg][col=lane&15] per 16x16 tile
    const int rbase = blockRow + wave * 16 + (lane >> 4) * 4;
#pragma unroll
    for (int t = 0; t < 8; t++) {
        int col = t * 16 + (lane & 15);
        float bv = bias[col];
#pragma unroll
        for (int r = 0; r < 4; r++) {
            int row = rbase + r;
            if (row < M) {
                float val = acc[t][r] + bv;
                if (RELU) val = (val > 0.f) ? val : NEG * val;
                C[(size_t)row * BN + col] = val;
            }
        }
    }
}

// ---------------- column sums (for mean over nodes) ----------------

__global__ void k_colsum(const float* __restrict__ h, float* __restrict__ outsum, int n) {
    int c = threadIdx.x;                 // 128 threads = 128 cols
    int base = blockIdx.x * 256;
    int lim = n - base; if (lim > 256) lim = 256;
    float acc = 0.f;
    for (int r = 0; r < lim; r++) acc += h[(size_t)(base + r) * H + c];
    atomicAdd(&outsum[c], acc);
}

// ---------------- finisher: means -> Wpred -> Wcls -> softmax ----------------

__global__ void k_final(const float* __restrict__ colsum, const float* __restrict__ Wpred,
                        const float* __restrict__ bpred, const float* __restrict__ Wcls,
                        const float* __restrict__ bcls, float* __restrict__ out, int n) {
    __shared__ float g[512];
    __shared__ float g2[128];
    __shared__ float lg[2];
    int t = threadIdx.x;  // 128 threads
    float invn = 1.0f / (float)n;
    for (int i = t; i < 512; i += 128) g[i] = colsum[i] * invn;
    __syncthreads();
    float acc = bpred[t];
    for (int i = 0; i < 512; i++) acc += g[i] * Wpred[i * 128 + t];
    g2[t] = acc;
    __syncthreads();
    if (t < 2) {
        float l = bcls[t];
        for (int j = 0; j < 128; j++) l += g2[j] * Wcls[j * 2 + t];
        lg[t] = l;
    }
    __syncthreads();
    if (t == 0) {
        float m = fmaxf(lg[0], lg[1]);
        float e0 = expf(lg[0] - m), e1 = expf(lg[1] - m);
        float s = e0 + e1;
        out[0] = e0 / s;
        out[1] = e1 / s;
    }
}

// ---------------- launch ----------------

extern "C" void kernel_launch(void* const* d_in, const int* in_sizes, int n_in,
                              void* d_out, int out_size, void* d_ws, size_t ws_size,
                              hipStream_t stream) {
    const float* node_feat = (const float*)d_in[0];
    // d_in[1] edge_feat, d_in[2] base_data: dead in the reference graph -> never touched
    const float* degree = (const float*)d_in[3];
    const float* Wn     = (const float*)d_in[4];
    const float* bn     = (const float*)d_in[5];
    const float* Wgcn   = (const float*)d_in[8];
    const float* bgcn   = (const float*)d_in[9];
    const float* Wpred  = (const float*)d_in[10];
    const float* bpred  = (const float*)d_in[11];
    const float* Wcls   = (const float*)d_in[12];
    const float* bcls   = (const float*)d_in[13];
    const int*   src    = (const int*)d_in[14];
    const int*   dst    = (const int*)d_in[15];
    float* out = (float*)d_out;

    const int N = in_sizes[3];        // degree is [N,1]
    const int E = in_sizes[14];       // src is [E]
    (void)n_in; (void)out_size; (void)ws_size;

    // carve workspace (re-poisoned each call: everything below is rewritten every call)
    char* p = (char*)d_ws;
    auto carve = [&](size_t bytes) { char* r = p; p += (bytes + 255) & ~(size_t)255; return r; };
    float* buf0   = (float*)carve((size_t)N * H * 4);   // h0
    float* buf1   = (float*)carve((size_t)N * H * 4);   // hcur
    float* buf2   = (float*)carve((size_t)N * H * 4);   // agg scratch
    int*   cnt    = (int*)carve((size_t)N * 4);
    int*   row_ptr= (int*)carve((size_t)(N + 1) * 4);
    int*   nxt    = (int*)carve((size_t)N * 4);
    int*   ssrc   = (int*)carve((size_t)E * 4);
    int*   part   = (int*)carve(256 * 4);
    float* rdeg   = (float*)carve((size_t)N * 4);
    float* colsum = (float*)carve(512 * 4);

    const int nblk = (N + 255) / 256;
    hipMemsetAsync(cnt, 0, (size_t)N * 4, stream);
    hipMemsetAsync(colsum, 0, 512 * 4, stream);

    k_rdeg<<<nblk, 256, 0, stream>>>(degree, rdeg, N);
    k_hist<<<(E + 255) / 256, 256, 0, stream>>>(dst, cnt, E);
    k_scan1<<<nblk, 256, 0, stream>>>(cnt, part, N);
    k_scan2<<<1, 256, 0, stream>>>(part, nblk);
    k_scan3<<<nblk, 256, 0, stream>>>(cnt, part, row_ptr, nxt, N, E);
    k_fill<<<(E + 255) / 256, 256, 0, stream>>>(src, dst, nxt, ssrc, E);

    const int gblk = (N + 63) / 64;
    // h0 = node_feat @ Wn + bn
    k_gemm<256, false><<<gblk, 256, 0, stream>>>(node_feat, Wn, bn, buf0, N);
    // initial fusion: hcur[v] = sum_{u->v} h0[u]
    k_agg<false><<<(N + 3) / 4, 256, 0, stream>>>(buf0, row_ptr, ssrc, rdeg, buf1, N);
    // stack mean contribution of h0
    k_colsum<<<nblk, 128, 0, stream>>>(buf0, colsum + 0, N);

    for (int l = 0; l < 3; l++) {
        k_agg<true><<<(N + 3) / 4, 256, 0, stream>>>(buf1, row_ptr, ssrc, rdeg, buf2, N);
        k_gemm<128, true><<<gblk, 256, 0, stream>>>(buf2, Wgcn, bgcn, buf1, N);
        k_colsum<<<nblk, 128, 0, stream>>>(buf1, colsum + (l + 1) * H, N);
    }

    k_final<<<1, 128, 0, stream>>>(colsum, Wpred, bpred, Wcls, bcls, out, N);
}

// Round 2
// 692.935 us; speedup vs baseline: 1.6028x; 1.6028x over previous
//
#include <hip/hip_runtime.h>
#include <hip/hip_bf16.h>

#define H 128
#define NEG 0.01f

typedef __bf16 bf16;
typedef bf16 bf16x4 __attribute__((ext_vector_type(4)));
typedef bf16 bf16x8 __attribute__((ext_vector_type(8)));
typedef float f32x4 __attribute__((ext_vector_type(4)));

// ---------------- CSR build ----------------

__global__ void k_rdeg(const float* __restrict__ deg, float* __restrict__ rdeg, int n) {
    int i = blockIdx.x * 256 + threadIdx.x;
    if (i < n) rdeg[i] = 1.0f / deg[i];
}

__global__ void k_hist(const int* __restrict__ dst, int* __restrict__ cnt, int e) {
    int i = blockIdx.x * 256 + threadIdx.x;
    if (i < e) atomicAdd(&cnt[dst[i]], 1);
}

__global__ void k_scan1(const int* __restrict__ cnt, int* __restrict__ part, int n) {
    __shared__ int sh[256];
    int i = blockIdx.x * 256 + threadIdx.x;
    sh[threadIdx.x] = (i < n) ? cnt[i] : 0;
    __syncthreads();
    for (int off = 128; off > 0; off >>= 1) {
        if (threadIdx.x < off) sh[threadIdx.x] += sh[threadIdx.x + off];
        __syncthreads();
    }
    if (threadIdx.x == 0) part[blockIdx.x] = sh[0];
}

__global__ void k_scan2(int* part, int nblk) {
    __shared__ int sh[256];
    int t = threadIdx.x;
    sh[t] = (t < nblk) ? part[t] : 0;
    __syncthreads();
    for (int off = 1; off < 256; off <<= 1) {
        int v = (t >= off) ? sh[t - off] : 0;
        __syncthreads();
        sh[t] += v;
        __syncthreads();
    }
    if (t < nblk) part[t] = (t == 0) ? 0 : sh[t - 1];
}

__global__ void k_scan3(const int* __restrict__ cnt, const int* __restrict__ part,
                        int* __restrict__ row_ptr, int* __restrict__ nxt, int n, int e) {
    __shared__ int sh[256];
    int t = threadIdx.x;
    int i = blockIdx.x * 256 + t;
    sh[t] = (i < n) ? cnt[i] : 0;
    __syncthreads();
    for (int off = 1; off < 256; off <<= 1) {
        int v = (t >= off) ? sh[t - off] : 0;
        __syncthreads();
        sh[t] += v;
        __syncthreads();
    }
    int excl = part[blockIdx.x] + ((t == 0) ? 0 : sh[t - 1]);
    if (i < n) { row_ptr[i] = excl; nxt[i] = excl; }
    if (i == 0) row_ptr[n] = e;
}

__global__ void k_fill(const int* __restrict__ src, const int* __restrict__ dst,
                       int* __restrict__ nxt, int* __restrict__ ssrc, int e) {
    int i = blockIdx.x * 256 + threadIdx.x;
    if (i < e) {
        int p = atomicAdd(&nxt[dst[i]], 1);
        ssrc[p] = src[i];
    }
}

// ---------------- aggregation (CSR gather, bf16, 4 edges in flight) ----------------
// one wave per node; 16 lanes (bf16x8 each) cover 128 cols of one edge; 4 edges/iter

__global__ __launch_bounds__(256)
void k_agg0(const bf16* __restrict__ hg, const int* __restrict__ row_ptr,
            const int* __restrict__ ssrc, const float* __restrict__ rdeg,
            float* __restrict__ hcur, bf16* __restrict__ hs, int n) {
    int v = blockIdx.x * 4 + (threadIdx.x >> 6);
    if (v >= n) return;
    int lane = threadIdx.x & 63;
    int g = lane >> 4, sub = lane & 15;
    int e0 = row_ptr[v], e1 = row_ptr[v + 1];
    float acc[8];
#pragma unroll
    for (int j = 0; j < 8; j++) acc[j] = 0.f;
    for (int e = e0 + g; e < e1; e += 4) {
        int s = ssrc[e];
        bf16x8 x = *(const bf16x8*)(hg + (size_t)s * H + sub * 8);
#pragma unroll
        for (int j = 0; j < 8; j++) acc[j] += (float)x[j];
    }
#pragma unroll
    for (int j = 0; j < 8; j++) acc[j] += __shfl_xor(acc[j], 16);
#pragma unroll
    for (int j = 0; j < 8; j++) acc[j] += __shfl_xor(acc[j], 32);
    if (g == 0) {
        float r = rdeg[v];
        float* o = hcur + (size_t)v * H + sub * 8;
        float4 lo = {acc[0], acc[1], acc[2], acc[3]};
        float4 hi = {acc[4], acc[5], acc[6], acc[7]};
        *(float4*)o = lo;
        *(float4*)(o + 4) = hi;
        bf16x8 w;
#pragma unroll
        for (int j = 0; j < 8; j++) w[j] = (bf16)(acc[j] * r);
        *(bf16x8*)(hs + (size_t)v * H + sub * 8) = w;
    }
}

// layer agg: out_bf16[v] = sum_u hs[u] + hcur[v]
__global__ __launch_bounds__(256)
void k_aggL(const bf16* __restrict__ hs, const int* __restrict__ row_ptr,
            const int* __restrict__ ssrc, const float* __restrict__ hcur,
            bf16* __restrict__ aggout, int n) {
    int v = blockIdx.x * 4 + (threadIdx.x >> 6);
    if (v >= n) return;
    int lane = threadIdx.x & 63;
    int g = lane >> 4, sub = lane & 15;
    int e0 = row_ptr[v], e1 = row_ptr[v + 1];
    float acc[8];
#pragma unroll
    for (int j = 0; j < 8; j++) acc[j] = 0.f;
    for (int e = e0 + g; e < e1; e += 4) {
        int s = ssrc[e];
        bf16x8 x = *(const bf16x8*)(hs + (size_t)s * H + sub * 8);
#pragma unroll
        for (int j = 0; j < 8; j++) acc[j] += (float)x[j];
    }
#pragma unroll
    for (int j = 0; j < 8; j++) acc[j] += __shfl_xor(acc[j], 16);
#pragma unroll
    for (int j = 0; j < 8; j++) acc[j] += __shfl_xor(acc[j], 32);
    if (g == 0) {
        const float* hv = hcur + (size_t)v * H + sub * 8;
        float4 lo = *(const float4*)hv;
        float4 hi = *(const float4*)(hv + 4);
        acc[0] += lo.x; acc[1] += lo.y; acc[2] += lo.z; acc[3] += lo.w;
        acc[4] += hi.x; acc[5] += hi.y; acc[6] += hi.z; acc[7] += hi.w;
        bf16x8 w;
#pragma unroll
        for (int j = 0; j < 8; j++) w[j] = (bf16)acc[j];
        *(bf16x8*)(aggout + (size_t)v * H + sub * 8) = w;
    }
}

// ---------------- GEMM0: C_bf16[M,128] = A_f32[M,256] @ Wn + bn, fused colsum ----------------

__global__ __launch_bounds__(256)
void k_gemm0(const float* __restrict__ A, const float* __restrict__ Bw,
             const float* __restrict__ bias, bf16* __restrict__ Cg,
             float* __restrict__ colsum, int M) {
    constexpr int K = 256, BM = 64, BN = 128, BK = 64, LDT = BK + 8;
    __shared__ alignas(16) bf16 As[BM][LDT];
    __shared__ alignas(16) bf16 Bs[BN][LDT];
    const int tid = threadIdx.x;
    const int wave = tid >> 6, lane = tid & 63;
    const int sub = lane & 15, rg = lane >> 4;
    const int blockRow = blockIdx.x * BM;

    f32x4 acc[8];
#pragma unroll
    for (int t = 0; t < 8; t++) acc[t] = (f32x4){0.f, 0.f, 0.f, 0.f};

    for (int k0 = 0; k0 < K; k0 += BK) {
#pragma unroll
        for (int it = 0; it < 4; it++) {
            int s = it * 256 + tid;
            int row = s >> 4, f4 = (s & 15) * 4;
            int grow = blockRow + row; if (grow > M - 1) grow = M - 1;
            const float4 v = *(const float4*)(A + (size_t)grow * K + k0 + f4);
            bf16x4 w = { (bf16)v.x, (bf16)v.y, (bf16)v.z, (bf16)v.w };
            *(bf16x4*)&As[row][f4] = w;
        }
#pragma unroll
        for (int it = 0; it < 8; it++) {
            int s = it * 256 + tid;
            int kr = s >> 5, f4 = (s & 31) * 4;
            const float4 v = *(const float4*)(Bw + (size_t)(k0 + kr) * BN + f4);
            Bs[f4 + 0][kr] = (bf16)v.x;
            Bs[f4 + 1][kr] = (bf16)v.y;
            Bs[f4 + 2][kr] = (bf16)v.z;
            Bs[f4 + 3][kr] = (bf16)v.w;
        }
        __syncthreads();
#pragma unroll
        for (int kk = 0; kk < BK; kk += 32) {
            bf16x8 af = *(const bf16x8*)&As[wave * 16 + sub][kk + rg * 8];
#pragma unroll
            for (int t = 0; t < 8; t++) {
                bf16x8 bfv = *(const bf16x8*)&Bs[t * 16 + sub][kk + rg * 8];
                acc[t] = __builtin_amdgcn_mfma_f32_16x16x32_bf16(af, bfv, acc[t], 0, 0, 0);
            }
        }
        __syncthreads();
    }
    // epilogue: write bf16 + fused colsum
    const int rbase = blockRow + wave * 16 + rg * 4;
    float lsum[8];
#pragma unroll
    for (int t = 0; t < 8; t++) lsum[t] = 0.f;
#pragma unroll
    for (int r = 0; r < 4; r++) {
        int row = rbase + r;
        if (row < M) {
#pragma unroll
            for (int t = 0; t < 8; t++) {
                int col = t * 16 + sub;
                float val = acc[t][r] + bias[col];
                lsum[t] += val;
                Cg[(size_t)row * BN + col] = (bf16)val;
            }
        }
    }
    float* red = (float*)&As[0][0];   // 128*17 floats <= As
#pragma unroll
    for (int t = 0; t < 8; t++) red[(t * 16 + sub) * 17 + (wave * 4 + rg)] = lsum[t];
    __syncthreads();
    if (tid < 128) {
        float s = 0.f;
#pragma unroll
        for (int i = 0; i < 16; i++) s += red[tid * 17 + i];
        atomicAdd(&colsum[tid], s);
    }
}

// ---------------- layer GEMM: leakyrelu(A_bf16[M,128] @ Wgcn + b), fused outputs ----------------

template<bool WRITE_NEXT>
__global__ __launch_bounds__(256)
void k_gemmL(const bf16* __restrict__ A, const float* __restrict__ Bw,
             const float* __restrict__ bias, const float* __restrict__ rdeg,
             float* __restrict__ hcur, bf16* __restrict__ hs,
             float* __restrict__ colsum, int M) {
    constexpr int BM = 64, BN = 128, BK = 128, LDT = BK + 8;
    __shared__ alignas(16) bf16 As[BM][LDT];
    __shared__ alignas(16) bf16 Bs[BN][LDT];
    const int tid = threadIdx.x;
    const int wave = tid >> 6, lane = tid & 63;
    const int sub = lane & 15, rg = lane >> 4;
    const int blockRow = blockIdx.x * BM;

    // stage A (bf16 direct, 16B per load)
#pragma unroll
    for (int it = 0; it < 4; it++) {
        int s = it * 256 + tid;
        int row = s >> 4, ch = (s & 15) * 8;
        int grow = blockRow + row; if (grow > M - 1) grow = M - 1;
        bf16x8 v = *(const bf16x8*)(A + (size_t)grow * BK + ch);
        *(bf16x8*)&As[row][ch] = v;
    }
    // stage B transposed (fp32 -> bf16)
#pragma unroll
    for (int it = 0; it < 16; it++) {
        int s = it * 256 + tid;
        int kr = s >> 5, f4 = (s & 31) * 4;
        const float4 v = *(const float4*)(Bw + (size_t)kr * BN + f4);
        Bs[f4 + 0][kr] = (bf16)v.x;
        Bs[f4 + 1][kr] = (bf16)v.y;
        Bs[f4 + 2][kr] = (bf16)v.z;
        Bs[f4 + 3][kr] = (bf16)v.w;
    }
    __syncthreads();

    f32x4 acc[8];
#pragma unroll
    for (int t = 0; t < 8; t++) acc[t] = (f32x4){0.f, 0.f, 0.f, 0.f};
#pragma unroll
    for (int kk = 0; kk < BK; kk += 32) {
        bf16x8 af = *(const bf16x8*)&As[wave * 16 + sub][kk + rg * 8];
#pragma unroll
        for (int t = 0; t < 8; t++) {
            bf16x8 bfv = *(const bf16x8*)&Bs[t * 16 + sub][kk + rg * 8];
            acc[t] = __builtin_amdgcn_mfma_f32_16x16x32_bf16(af, bfv, acc[t], 0, 0, 0);
        }
    }
    __syncthreads();

    const int rbase = blockRow + wave * 16 + rg * 4;
    float lsum[8];
#pragma unroll
    for (int t = 0; t < 8; t++) lsum[t] = 0.f;
#pragma unroll
    for (int r = 0; r < 4; r++) {
        int row = rbase + r;
        if (row < M) {
            float rd = WRITE_NEXT ? rdeg[row] : 0.f;
#pragma unroll
            for (int t = 0; t < 8; t++) {
                int col = t * 16 + sub;
                float val = acc[t][r] + bias[col];
                val = (val > 0.f) ? val : NEG * val;
                lsum[t] += val;
                if (WRITE_NEXT) {
                    hcur[(size_t)row * BN + col] = val;
                    hs[(size_t)row * BN + col] = (bf16)(val * rd);
                }
            }
        }
    }
    float* red = (float*)&As[0][0];
#pragma unroll
    for (int t = 0; t < 8; t++) red[(t * 16 + sub) * 17 + (wave * 4 + rg)] = lsum[t];
    __syncthreads();
    if (tid < 128) {
        float s = 0.f;
#pragma unroll
        for (int i = 0; i < 16; i++) s += red[tid * 17 + i];
        atomicAdd(&colsum[tid], s);
    }
}

// ---------------- finisher ----------------

__global__ void k_final(const float* __restrict__ colsum, const float* __restrict__ Wpred,
                        const float* __restrict__ bpred, const float* __restrict__ Wcls,
                        const float* __restrict__ bcls, float* __restrict__ out, int n) {
    __shared__ float g[512];
    __shared__ float g2[128];
    __shared__ float lg[2];
    int t = threadIdx.x;  // 128 threads
    float invn = 1.0f / (float)n;
    for (int i = t; i < 512; i += 128) g[i] = colsum[i] * invn;
    __syncthreads();
    float acc = bpred[t];
    for (int i = 0; i < 512; i++) acc += g[i] * Wpred[i * 128 + t];
    g2[t] = acc;
    __syncthreads();
    if (t < 2) {
        float l = bcls[t];
        for (int j = 0; j < 128; j++) l += g2[j] * Wcls[j * 2 + t];
        lg[t] = l;
    }
    __syncthreads();
    if (t == 0) {
        float m = fmaxf(lg[0], lg[1]);
        float e0 = expf(lg[0] - m), e1 = expf(lg[1] - m);
        float s = e0 + e1;
        out[0] = e0 / s;
        out[1] = e1 / s;
    }
}

// ---------------- launch ----------------

extern "C" void kernel_launch(void* const* d_in, const int* in_sizes, int n_in,
                              void* d_out, int out_size, void* d_ws, size_t ws_size,
                              hipStream_t stream) {
    const float* node_feat = (const float*)d_in[0];
    const float* degree = (const float*)d_in[3];
    const float* Wn     = (const float*)d_in[4];
    const float* bn     = (const float*)d_in[5];
    const float* Wgcn   = (const float*)d_in[8];
    const float* bgcn   = (const float*)d_in[9];
    const float* Wpred  = (const float*)d_in[10];
    const float* bpred  = (const float*)d_in[11];
    const float* Wcls   = (const float*)d_in[12];
    const float* bcls   = (const float*)d_in[13];
    const int*   src    = (const int*)d_in[14];
    const int*   dst    = (const int*)d_in[15];
    float* out = (float*)d_out;

    const int N = in_sizes[3];
    const int E = in_sizes[14];
    (void)n_in; (void)out_size; (void)ws_size;

    char* p = (char*)d_ws;
    auto carve = [&](size_t bytes) { char* r = p; p += (bytes + 255) & ~(size_t)255; return r; };
    bf16*  h0g    = (bf16*)carve((size_t)N * H * 2);    // bf16 gather copy of h0
    float* hcur   = (float*)carve((size_t)N * H * 4);   // fp32 running hidden (self-add)
    bf16*  hsb    = (bf16*)carve((size_t)N * H * 2);    // bf16 pre-scaled gather copy
    bf16*  aggb   = (bf16*)carve((size_t)N * H * 2);    // bf16 agg output -> GEMM A
    int*   cnt    = (int*)carve((size_t)N * 4);
    int*   row_ptr= (int*)carve((size_t)(N + 1) * 4);
    int*   nxt    = (int*)carve((size_t)N * 4);
    int*   ssrc   = (int*)carve((size_t)E * 4);
    int*   part   = (int*)carve(256 * 4);
    float* rdeg   = (float*)carve((size_t)N * 4);
    float* colsum = (float*)carve(512 * 4);

    const int nblk = (N + 255) / 256;
    hipMemsetAsync(cnt, 0, (size_t)N * 4, stream);
    hipMemsetAsync(colsum, 0, 512 * 4, stream);

    k_rdeg<<<nblk, 256, 0, stream>>>(degree, rdeg, N);
    k_hist<<<(E + 255) / 256, 256, 0, stream>>>(dst, cnt, E);
    k_scan1<<<nblk, 256, 0, stream>>>(cnt, part, N);
    k_scan2<<<1, 256, 0, stream>>>(part, nblk);
    k_scan3<<<nblk, 256, 0, stream>>>(cnt, part, row_ptr, nxt, N, E);
    k_fill<<<(E + 255) / 256, 256, 0, stream>>>(src, dst, nxt, ssrc, E);

    const int gblk = (N + 63) / 64;
    const int ablk = (N + 3) / 4;

    // h0 = node_feat @ Wn + bn  (bf16 out + colsum[0:128))
    k_gemm0<<<gblk, 256, 0, stream>>>(node_feat, Wn, bn, h0g, colsum, N);
    // initial fusion: hcur[v] = sum h0[u]; hs[v] = hcur[v]*rdeg[v]
    k_agg0<<<ablk, 256, 0, stream>>>(h0g, row_ptr, ssrc, rdeg, hcur, hsb, N);

    // layers
    k_aggL<<<ablk, 256, 0, stream>>>(hsb, row_ptr, ssrc, hcur, aggb, N);
    k_gemmL<true><<<gblk, 256, 0, stream>>>(aggb, Wgcn, bgcn, rdeg, hcur, hsb, colsum + 1 * H, N);
    k_aggL<<<ablk, 256, 0, stream>>>(hsb, row_ptr, ssrc, hcur, aggb, N);
    k_gemmL<true><<<gblk, 256, 0, stream>>>(aggb, Wgcn, bgcn, rdeg, hcur, hsb, colsum + 2 * H, N);
    k_aggL<<<ablk, 256, 0, stream>>>(hsb, row_ptr, ssrc, hcur, aggb, N);
    k_gemmL<false><<<gblk, 256, 0, stream>>>(aggb, Wgcn, bgcn, rdeg, hcur, hsb, colsum + 3 * H, N);

    k_final<<<1, 128, 0, stream>>>(colsum, Wpred, bpred, Wcls, bcls, out, N);
}

// Round 3
// 661.603 us; speedup vs baseline: 1.6787x; 1.0474x over previous
//
#include <hip/hip_runtime.h>
#include <hip/hip_bf16.h>

#define H 128
#define NEG 0.01f

typedef __bf16 bf16;
typedef bf16 bf16x4 __attribute__((ext_vector_type(4)));
typedef bf16 bf16x8 __attribute__((ext_vector_type(8)));
typedef float f32x4 __attribute__((ext_vector_type(4)));

// ---------------- CSR build ----------------

__global__ void k_hist(const int* __restrict__ dst, int* __restrict__ cnt, int e) {
    int i = blockIdx.x * 256 + threadIdx.x;
    if (i < e) atomicAdd(&cnt[dst[i]], 1);
}

__global__ void k_scan1(const int* __restrict__ cnt, int* __restrict__ part, int n) {
    __shared__ int sh[256];
    int i = blockIdx.x * 256 + threadIdx.x;
    sh[threadIdx.x] = (i < n) ? cnt[i] : 0;
    __syncthreads();
    for (int off = 128; off > 0; off >>= 1) {
        if (threadIdx.x < off) sh[threadIdx.x] += sh[threadIdx.x + off];
        __syncthreads();
    }
    if (threadIdx.x == 0) part[blockIdx.x] = sh[0];
}

__global__ void k_scan2(int* part, int nblk) {
    __shared__ int sh[256];
    int t = threadIdx.x;
    sh[t] = (t < nblk) ? part[t] : 0;
    __syncthreads();
    for (int off = 1; off < 256; off <<= 1) {
        int v = (t >= off) ? sh[t - off] : 0;
        __syncthreads();
        sh[t] += v;
        __syncthreads();
    }
    if (t < nblk) part[t] = (t == 0) ? 0 : sh[t - 1];
}

__global__ void k_scan3(const int* __restrict__ cnt, const int* __restrict__ part,
                        int* __restrict__ row_ptr, int* __restrict__ nxt, int n, int e) {
    __shared__ int sh[256];
    int t = threadIdx.x;
    int i = blockIdx.x * 256 + t;
    sh[t] = (i < n) ? cnt[i] : 0;
    __syncthreads();
    for (int off = 1; off < 256; off <<= 1) {
        int v = (t >= off) ? sh[t - off] : 0;
        __syncthreads();
        sh[t] += v;
        __syncthreads();
    }
    int excl = part[blockIdx.x] + ((t == 0) ? 0 : sh[t - 1]);
    if (i < n) { row_ptr[i] = excl; nxt[i] = excl; }
    if (i == 0) row_ptr[n] = e;
}

__global__ void k_fill(const int* __restrict__ src, const int* __restrict__ dst,
                       int* __restrict__ nxt, int* __restrict__ ssrc, int e) {
    int i = blockIdx.x * 256 + threadIdx.x;
    if (i < e) {
        int p = atomicAdd(&nxt[dst[i]], 1);
        ssrc[p] = src[i];
    }
}

// ---------------- aggregation: 1 wave/node, 16-lane groups, 4 edges in flight/group ----------------
// k_agg0: hs[v] = (sum_{u->v} hg[u]) / deg[v]          (bf16 out)
__global__ __launch_bounds__(256)
void k_agg0(const bf16* __restrict__ hg, const int* __restrict__ row_ptr,
            const int* __restrict__ ssrc, const float* __restrict__ deg,
            bf16* __restrict__ hs, int n) {
    int v = blockIdx.x * 4 + (threadIdx.x >> 6);
    if (v >= n) return;
    int lane = threadIdx.x & 63;
    int g = lane >> 4, sub = lane & 15;
    int e0 = row_ptr[v], e1 = row_ptr[v + 1];
    float d = deg[v];
    float acc[8];
#pragma unroll
    for (int k = 0; k < 8; k++) acc[k] = 0.f;
    for (int base = e0; base < e1; base += 16) {
        int mye = base + g * 4;
        int idx[4]; float w[4];
#pragma unroll
        for (int j = 0; j < 4; j++) {
            int e = mye + j;
            w[j] = (e < e1) ? 1.0f : 0.0f;
            idx[j] = ssrc[e < e1 ? e : e1 - 1];
        }
        bf16x8 x0 = *(const bf16x8*)(hg + (size_t)idx[0] * H + sub * 8);
        bf16x8 x1 = *(const bf16x8*)(hg + (size_t)idx[1] * H + sub * 8);
        bf16x8 x2 = *(const bf16x8*)(hg + (size_t)idx[2] * H + sub * 8);
        bf16x8 x3 = *(const bf16x8*)(hg + (size_t)idx[3] * H + sub * 8);
#pragma unroll
        for (int k = 0; k < 8; k++) acc[k] = fmaf(w[0], (float)x0[k], acc[k]);
#pragma unroll
        for (int k = 0; k < 8; k++) acc[k] = fmaf(w[1], (float)x1[k], acc[k]);
#pragma unroll
        for (int k = 0; k < 8; k++) acc[k] = fmaf(w[2], (float)x2[k], acc[k]);
#pragma unroll
        for (int k = 0; k < 8; k++) acc[k] = fmaf(w[3], (float)x3[k], acc[k]);
    }
#pragma unroll
    for (int k = 0; k < 8; k++) acc[k] += __shfl_xor(acc[k], 16);
#pragma unroll
    for (int k = 0; k < 8; k++) acc[k] += __shfl_xor(acc[k], 32);
    if (g == 0) {
        float r = 1.0f / d;
        bf16x8 wv;
#pragma unroll
        for (int k = 0; k < 8; k++) wv[k] = (bf16)(acc[k] * r);
        *(bf16x8*)(hs + (size_t)v * H + sub * 8) = wv;
    }
}

// k_aggL: aggout[v] = sum_{u->v} hs[u] + hs[v]*deg[v]   (hs is pre-scaled h/deg; bf16 out)
__global__ __launch_bounds__(256)
void k_aggL(const bf16* __restrict__ hs, const int* __restrict__ row_ptr,
            const int* __restrict__ ssrc, const float* __restrict__ deg,
            bf16* __restrict__ aggout, int n) {
    int v = blockIdx.x * 4 + (threadIdx.x >> 6);
    if (v >= n) return;
    int lane = threadIdx.x & 63;
    int g = lane >> 4, sub = lane & 15;
    int e0 = row_ptr[v], e1 = row_ptr[v + 1];
    // issue self row + deg early (overlaps with edge loop)
    bf16x8 sv = *(const bf16x8*)(hs + (size_t)v * H + sub * 8);
    float d = deg[v];
    float acc[8];
#pragma unroll
    for (int k = 0; k < 8; k++) acc[k] = 0.f;
    for (int base = e0; base < e1; base += 16) {
        int mye = base + g * 4;
        int idx[4]; float w[4];
#pragma unroll
        for (int j = 0; j < 4; j++) {
            int e = mye + j;
            w[j] = (e < e1) ? 1.0f : 0.0f;
            idx[j] = ssrc[e < e1 ? e : e1 - 1];
        }
        bf16x8 x0 = *(const bf16x8*)(hs + (size_t)idx[0] * H + sub * 8);
        bf16x8 x1 = *(const bf16x8*)(hs + (size_t)idx[1] * H + sub * 8);
        bf16x8 x2 = *(const bf16x8*)(hs + (size_t)idx[2] * H + sub * 8);
        bf16x8 x3 = *(const bf16x8*)(hs + (size_t)idx[3] * H + sub * 8);
#pragma unroll
        for (int k = 0; k < 8; k++) acc[k] = fmaf(w[0], (float)x0[k], acc[k]);
#pragma unroll
        for (int k = 0; k < 8; k++) acc[k] = fmaf(w[1], (float)x1[k], acc[k]);
#pragma unroll
        for (int k = 0; k < 8; k++) acc[k] = fmaf(w[2], (float)x2[k], acc[k]);
#pragma unroll
        for (int k = 0; k < 8; k++) acc[k] = fmaf(w[3], (float)x3[k], acc[k]);
    }
#pragma unroll
    for (int k = 0; k < 8; k++) acc[k] += __shfl_xor(acc[k], 16);
#pragma unroll
    for (int k = 0; k < 8; k++) acc[k] += __shfl_xor(acc[k], 32);
    if (g == 0) {
        bf16x8 wv;
#pragma unroll
        for (int k = 0; k < 8; k++) wv[k] = (bf16)(acc[k] + (float)sv[k] * d);
        *(bf16x8*)(aggout + (size_t)v * H + sub * 8) = wv;
    }
}

// ---------------- GEMM0: h0_bf16[M,128] = A_f32[M,256] @ Wn + bn, fused colsum ----------------

__global__ __launch_bounds__(256)
void k_gemm0(const float* __restrict__ A, const float* __restrict__ Bw,
             const float* __restrict__ bias, bf16* __restrict__ Cg,
             float* __restrict__ colsum, int M) {
    constexpr int K = 256, BM = 64, BN = 128, BK = 64, LDT = BK + 8;
    __shared__ alignas(16) bf16 As[BM][LDT];
    __shared__ alignas(16) bf16 Bs[BN][LDT];
    __shared__ float cs[128];
    const int tid = threadIdx.x;
    const int wave = tid >> 6, lane = tid & 63;
    const int sub = lane & 15, rg = lane >> 4;
    const int blockRow = blockIdx.x * BM;
    if (tid < 128) cs[tid] = 0.f;

    f32x4 acc[8];
#pragma unroll
    for (int t = 0; t < 8; t++) acc[t] = (f32x4){0.f, 0.f, 0.f, 0.f};

    for (int k0 = 0; k0 < K; k0 += BK) {
#pragma unroll
        for (int it = 0; it < 4; it++) {
            int s = it * 256 + tid;
            int row = s >> 4, f4 = (s & 15) * 4;
            int grow = blockRow + row; if (grow > M - 1) grow = M - 1;
            const float4 v = *(const float4*)(A + (size_t)grow * K + k0 + f4);
            bf16x4 w = { (bf16)v.x, (bf16)v.y, (bf16)v.z, (bf16)v.w };
            *(bf16x4*)&As[row][f4] = w;
        }
#pragma unroll
        for (int it = 0; it < 8; it++) {
            int s = it * 256 + tid;
            int kr = s >> 5, f4 = (s & 31) * 4;
            const float4 v = *(const float4*)(Bw + (size_t)(k0 + kr) * BN + f4);
            Bs[f4 + 0][kr] = (bf16)v.x;
            Bs[f4 + 1][kr] = (bf16)v.y;
            Bs[f4 + 2][kr] = (bf16)v.z;
            Bs[f4 + 3][kr] = (bf16)v.w;
        }
        __syncthreads();
#pragma unroll
        for (int kk = 0; kk < BK; kk += 32) {
            bf16x8 af = *(const bf16x8*)&As[wave * 16 + sub][kk + rg * 8];
#pragma unroll
            for (int t = 0; t < 8; t++) {
                bf16x8 bfv = *(const bf16x8*)&Bs[t * 16 + sub][kk + rg * 8];
                acc[t] = __builtin_amdgcn_mfma_f32_16x16x32_bf16(af, bfv, acc[t], 0, 0, 0);
            }
        }
        __syncthreads();
    }
    const int rbase = blockRow + wave * 16 + rg * 4;
    float lsum[8];
#pragma unroll
    for (int t = 0; t < 8; t++) lsum[t] = 0.f;
#pragma unroll
    for (int r = 0; r < 4; r++) {
        int row = rbase + r;
        if (row < M) {
#pragma unroll
            for (int t = 0; t < 8; t++) {
                int col = t * 16 + sub;
                float val = acc[t][r] + bias[col];
                lsum[t] += val;
                Cg[(size_t)row * BN + col] = (bf16)val;
            }
        }
    }
    // reduce lsum over the 4 row-groups (lane bits 4-5), then LDS, then 1 atomic/col/block
#pragma unroll
    for (int t = 0; t < 8; t++) {
        lsum[t] += __shfl_xor(lsum[t], 16);
        lsum[t] += __shfl_xor(lsum[t], 32);
    }
    if (rg == 0) {
#pragma unroll
        for (int t = 0; t < 8; t++) atomicAdd(&cs[t * 16 + sub], lsum[t]);
    }
    __syncthreads();
    if (tid < 128) atomicAdd(&colsum[tid], cs[tid]);
}

// ---------------- layer GEMM: leakyrelu(A_bf16[M,128] @ Wgcn + b); writes hs=val/deg ----------------

template<bool WRITE_NEXT>
__global__ __launch_bounds__(256)
void k_gemmL(const bf16* __restrict__ A, const float* __restrict__ Bw,
             const float* __restrict__ bias, const float* __restrict__ deg,
             bf16* __restrict__ hs, float* __restrict__ colsum, int M) {
    constexpr int BM = 64, BN = 128, BK = 128, LDT = BK + 8;
    __shared__ alignas(16) bf16 As[BM][LDT];
    __shared__ alignas(16) bf16 Bs[BN][LDT];
    __shared__ float cs[128];
    const int tid = threadIdx.x;
    const int wave = tid >> 6, lane = tid & 63;
    const int sub = lane & 15, rg = lane >> 4;
    const int blockRow = blockIdx.x * BM;
    if (tid < 128) cs[tid] = 0.f;

#pragma unroll
    for (int it = 0; it < 4; it++) {
        int s = it * 256 + tid;
        int row = s >> 4, ch = (s & 15) * 8;
        int grow = blockRow + row; if (grow > M - 1) grow = M - 1;
        bf16x8 v = *(const bf16x8*)(A + (size_t)grow * BK + ch);
        *(bf16x8*)&As[row][ch] = v;
    }
#pragma unroll
    for (int it = 0; it < 16; it++) {
        int s = it * 256 + tid;
        int kr = s >> 5, f4 = (s & 31) * 4;
        const float4 v = *(const float4*)(Bw + (size_t)kr * BN + f4);
        Bs[f4 + 0][kr] = (bf16)v.x;
        Bs[f4 + 1][kr] = (bf16)v.y;
        Bs[f4 + 2][kr] = (bf16)v.z;
        Bs[f4 + 3][kr] = (bf16)v.w;
    }
    __syncthreads();

    f32x4 acc[8];
#pragma unroll
    for (int t = 0; t < 8; t++) acc[t] = (f32x4){0.f, 0.f, 0.f, 0.f};
#pragma unroll
    for (int kk = 0; kk < BK; kk += 32) {
        bf16x8 af = *(const bf16x8*)&As[wave * 16 + sub][kk + rg * 8];
#pragma unroll
        for (int t = 0; t < 8; t++) {
            bf16x8 bfv = *(const bf16x8*)&Bs[t * 16 + sub][kk + rg * 8];
            acc[t] = __builtin_amdgcn_mfma_f32_16x16x32_bf16(af, bfv, acc[t], 0, 0, 0);
        }
    }
    __syncthreads();

    const int rbase = blockRow + wave * 16 + rg * 4;
    float lsum[8];
#pragma unroll
    for (int t = 0; t < 8; t++) lsum[t] = 0.f;
#pragma unroll
    for (int r = 0; r < 4; r++) {
        int row = rbase + r;
        if (row < M) {
            float rd = WRITE_NEXT ? (1.0f / deg[row]) : 0.f;
#pragma unroll
            for (int t = 0; t < 8; t++) {
                int col = t * 16 + sub;
                float val = acc[t][r] + bias[col];
                val = (val > 0.f) ? val : NEG * val;
                lsum[t] += val;
                if (WRITE_NEXT) hs[(size_t)row * BN + col] = (bf16)(val * rd);
            }
        }
    }
#pragma unroll
    for (int t = 0; t < 8; t++) {
        lsum[t] += __shfl_xor(lsum[t], 16);
        lsum[t] += __shfl_xor(lsum[t], 32);
    }
    if (rg == 0) {
#pragma unroll
        for (int t = 0; t < 8; t++) atomicAdd(&cs[t * 16 + sub], lsum[t]);
    }
    __syncthreads();
    if (tid < 128) atomicAdd(&colsum[tid], cs[tid]);
}

// ---------------- finisher ----------------

__global__ void k_final(const float* __restrict__ colsum, const float* __restrict__ Wpred,
                        const float* __restrict__ bpred, const float* __restrict__ Wcls,
                        const float* __restrict__ bcls, float* __restrict__ out, int n) {
    __shared__ float g[512];
    __shared__ float g2[128];
    __shared__ float lg[2];
    int t = threadIdx.x;  // 128 threads
    float invn = 1.0f / (float)n;
    for (int i = t; i < 512; i += 128) g[i] = colsum[i] * invn;
    __syncthreads();
    float acc = bpred[t];
    for (int i = 0; i < 512; i++) acc += g[i] * Wpred[i * 128 + t];
    g2[t] = acc;
    __syncthreads();
    if (t < 2) {
        float l = bcls[t];
        for (int j = 0; j < 128; j++) l += g2[j] * Wcls[j * 2 + t];
        lg[t] = l;
    }
    __syncthreads();
    if (t == 0) {
        float m = fmaxf(lg[0], lg[1]);
        float e0 = expf(lg[0] - m), e1 = expf(lg[1] - m);
        float s = e0 + e1;
        out[0] = e0 / s;
        out[1] = e1 / s;
    }
}

// ---------------- launch ----------------

extern "C" void kernel_launch(void* const* d_in, const int* in_sizes, int n_in,
                              void* d_out, int out_size, void* d_ws, size_t ws_size,
                              hipStream_t stream) {
    const float* node_feat = (const float*)d_in[0];
    const float* degree = (const float*)d_in[3];
    const float* Wn     = (const float*)d_in[4];
    const float* bn     = (const float*)d_in[5];
    const float* Wgcn   = (const float*)d_in[8];
    const float* bgcn   = (const float*)d_in[9];
    const float* Wpred  = (const float*)d_in[10];
    const float* bpred  = (const float*)d_in[11];
    const float* Wcls   = (const float*)d_in[12];
    const float* bcls   = (const float*)d_in[13];
    const int*   src    = (const int*)d_in[14];
    const int*   dst    = (const int*)d_in[15];
    float* out = (float*)d_out;

    const int N = in_sizes[3];
    const int E = in_sizes[14];
    (void)n_in; (void)out_size; (void)ws_size;

    char* p = (char*)d_ws;
    auto carve = [&](size_t bytes) { char* r = p; p += (bytes + 255) & ~(size_t)255; return r; };
    bf16*  h0g    = (bf16*)carve((size_t)N * H * 2);    // bf16 h0 (gather table for fusion)
    bf16*  hsb    = (bf16*)carve((size_t)N * H * 2);    // bf16 pre-scaled hidden (gather table)
    bf16*  aggb   = (bf16*)carve((size_t)N * H * 2);    // bf16 agg output -> GEMM A
    int*   cnt    = (int*)carve((size_t)N * 4);
    int*   row_ptr= (int*)carve((size_t)(N + 1) * 4);
    int*   nxt    = (int*)carve((size_t)N * 4);
    int*   ssrc   = (int*)carve((size_t)E * 4);
    int*   part   = (int*)carve(256 * 4);
    float* colsum = (float*)carve(512 * 4);

    const int nblk = (N + 255) / 256;
    hipMemsetAsync(cnt, 0, (size_t)N * 4, stream);
    hipMemsetAsync(colsum, 0, 512 * 4, stream);

    k_hist<<<(E + 255) / 256, 256, 0, stream>>>(dst, cnt, E);
    k_scan1<<<nblk, 256, 0, stream>>>(cnt, part, N);
    k_scan2<<<1, 256, 0, stream>>>(part, nblk);
    k_scan3<<<nblk, 256, 0, stream>>>(cnt, part, row_ptr, nxt, N, E);
    k_fill<<<(E + 255) / 256, 256, 0, stream>>>(src, dst, nxt, ssrc, E);

    const int gblk = (N + 63) / 64;
    const int ablk = (N + 3) / 4;

    // h0 = node_feat @ Wn + bn  (bf16 out + colsum[0:128))
    k_gemm0<<<gblk, 256, 0, stream>>>(node_feat, Wn, bn, h0g, colsum, N);
    // fusion: hsb[v] = (sum_{u->v} h0[u]) / deg[v]
    k_agg0<<<ablk, 256, 0, stream>>>(h0g, row_ptr, ssrc, degree, hsb, N);

    // layers: agg (gather + self) -> gemm (leakyrelu, writes next hsb + colsum)
    k_aggL<<<ablk, 256, 0, stream>>>(hsb, row_ptr, ssrc, degree, aggb, N);
    k_gemmL<true><<<gblk, 256, 0, stream>>>(aggb, Wgcn, bgcn, degree, hsb, colsum + 1 * H, N);
    k_aggL<<<ablk, 256, 0, stream>>>(hsb, row_ptr, ssrc, degree, aggb, N);
    k_gemmL<true><<<gblk, 256, 0, stream>>>(aggb, Wgcn, bgcn, degree, hsb, colsum + 2 * H, N);
    k_aggL<<<ablk, 256, 0, stream>>>(hsb, row_ptr, ssrc, degree, aggb, N);
    k_gemmL<false><<<gblk, 256, 0, stream>>>(aggb, Wgcn, bgcn, degree, hsb, colsum + 3 * H, N);

    k_final<<<1, 128, 0, stream>>>(colsum, Wpred, bpred, Wcls, bcls, out, N);
}

// Round 4
// 632.407 us; speedup vs baseline: 1.7562x; 1.0462x over previous
//
#include <hip/hip_runtime.h>
#include <hip/hip_bf16.h>

#define H 128
#define NEG 0.01f

typedef __bf16 bf16;
typedef bf16 bf16x4 __attribute__((ext_vector_type(4)));
typedef bf16 bf16x8 __attribute__((ext_vector_type(8)));
typedef float f32x4 __attribute__((ext_vector_type(4)));
typedef float f32x2 __attribute__((ext_vector_type(2)));
typedef unsigned int u32;

// ---- fp8 e4m3 (OCP on gfx950) pack/unpack: 8 elems <-> 8 bytes (uint2) ----
__device__ __forceinline__ void dec8(uint2 p, float f[8]) {
    f32x2 a = __builtin_amdgcn_cvt_pk_f32_fp8(p.x, false);
    f32x2 b = __builtin_amdgcn_cvt_pk_f32_fp8(p.x, true);
    f32x2 c = __builtin_amdgcn_cvt_pk_f32_fp8(p.y, false);
    f32x2 d = __builtin_amdgcn_cvt_pk_f32_fp8(p.y, true);
    f[0] = a[0]; f[1] = a[1]; f[2] = b[0]; f[3] = b[1];
    f[4] = c[0]; f[5] = c[1]; f[6] = d[0]; f[7] = d[1];
}
__device__ __forceinline__ uint2 enc8(const float f[8]) {
    int lo = 0, hi = 0;
    lo = __builtin_amdgcn_cvt_pk_fp8_f32(f[0], f[1], lo, false);
    lo = __builtin_amdgcn_cvt_pk_fp8_f32(f[2], f[3], lo, true);
    hi = __builtin_amdgcn_cvt_pk_fp8_f32(f[4], f[5], hi, false);
    hi = __builtin_amdgcn_cvt_pk_fp8_f32(f[6], f[7], hi, true);
    uint2 r; r.x = (u32)lo; r.y = (u32)hi; return r;
}

// ---------------- CSR build ----------------

__global__ void k_hist(const int* __restrict__ dst, int* __restrict__ cnt, int e) {
    int i = blockIdx.x * 256 + threadIdx.x;
    if (i < e) atomicAdd(&cnt[dst[i]], 1);
}

__global__ void k_scan1(const int* __restrict__ cnt, int* __restrict__ part, int n) {
    __shared__ int sh[256];
    int i = blockIdx.x * 256 + threadIdx.x;
    sh[threadIdx.x] = (i < n) ? cnt[i] : 0;
    __syncthreads();
    for (int off = 128; off > 0; off >>= 1) {
        if (threadIdx.x < off) sh[threadIdx.x] += sh[threadIdx.x + off];
        __syncthreads();
    }
    if (threadIdx.x == 0) part[blockIdx.x] = sh[0];
}

__global__ void k_scan2(int* part, int nblk) {
    __shared__ int sh[256];
    int t = threadIdx.x;
    sh[t] = (t < nblk) ? part[t] : 0;
    __syncthreads();
    for (int off = 1; off < 256; off <<= 1) {
        int v = (t >= off) ? sh[t - off] : 0;
        __syncthreads();
        sh[t] += v;
        __syncthreads();
    }
    if (t < nblk) part[t] = (t == 0) ? 0 : sh[t - 1];
}

__global__ void k_scan3(const int* __restrict__ cnt, const int* __restrict__ part,
                        int* __restrict__ row_ptr, int* __restrict__ nxt, int n, int e) {
    __shared__ int sh[256];
    int t = threadIdx.x;
    int i = blockIdx.x * 256 + t;
    sh[t] = (i < n) ? cnt[i] : 0;
    __syncthreads();
    for (int off = 1; off < 256; off <<= 1) {
        int v = (t >= off) ? sh[t - off] : 0;
        __syncthreads();
        sh[t] += v;
        __syncthreads();
    }
    int excl = part[blockIdx.x] + ((t == 0) ? 0 : sh[t - 1]);
    if (i < n) { row_ptr[i] = excl; nxt[i] = excl; }
    if (i == 0) row_ptr[n] = e;
}

__global__ void k_fill(const int* __restrict__ src, const int* __restrict__ dst,
                       int* __restrict__ nxt, int* __restrict__ ssrc, int e) {
    int i = blockIdx.x * 256 + threadIdx.x;
    if (i < e) {
        int p = atomicAdd(&nxt[dst[i]], 1);
        ssrc[p] = src[i];
    }
}

// ---------------- aggregation: 1 wave/node, 16-lane groups, 4 edges in flight/group ----------------
// tables are fp8: one node row = 128 B = 16 uint2; lane sub owns cols [sub*8, sub*8+8)

// k_agg0: hs[v] = (sum_{u->v} h0[u]) / deg[v]     (fp8 in, fp8 out)
__global__ __launch_bounds__(256)
void k_agg0(const uint2* __restrict__ hg, const int* __restrict__ row_ptr,
            const int* __restrict__ ssrc, const float* __restrict__ deg,
            uint2* __restrict__ hs, int n) {
    int v = blockIdx.x * 4 + (threadIdx.x >> 6);
    if (v >= n) return;
    int lane = threadIdx.x & 63;
    int g = lane >> 4, sub = lane & 15;
    int e0 = row_ptr[v], e1 = row_ptr[v + 1];
    float d = deg[v];
    float acc[8];
#pragma unroll
    for (int k = 0; k < 8; k++) acc[k] = 0.f;
    for (int base = e0; base < e1; base += 16) {
        int mye = base + g * 4;
        int idx[4]; float w[4];
#pragma unroll
        for (int j = 0; j < 4; j++) {
            int e = mye + j;
            w[j] = (e < e1) ? 1.0f : 0.0f;
            idx[j] = ssrc[e < e1 ? e : e1 - 1];
        }
        uint2 x0 = hg[(size_t)idx[0] * 16 + sub];
        uint2 x1 = hg[(size_t)idx[1] * 16 + sub];
        uint2 x2 = hg[(size_t)idx[2] * 16 + sub];
        uint2 x3 = hg[(size_t)idx[3] * 16 + sub];
        float f0[8], f1[8], f2[8], f3[8];
        dec8(x0, f0); dec8(x1, f1); dec8(x2, f2); dec8(x3, f3);
#pragma unroll
        for (int k = 0; k < 8; k++) acc[k] = fmaf(w[0], f0[k], acc[k]);
#pragma unroll
        for (int k = 0; k < 8; k++) acc[k] = fmaf(w[1], f1[k], acc[k]);
#pragma unroll
        for (int k = 0; k < 8; k++) acc[k] = fmaf(w[2], f2[k], acc[k]);
#pragma unroll
        for (int k = 0; k < 8; k++) acc[k] = fmaf(w[3], f3[k], acc[k]);
    }
#pragma unroll
    for (int k = 0; k < 8; k++) acc[k] += __shfl_xor(acc[k], 16);
#pragma unroll
    for (int k = 0; k < 8; k++) acc[k] += __shfl_xor(acc[k], 32);
    if (g == 0) {
        float r = 1.0f / d;
        float o[8];
#pragma unroll
        for (int k = 0; k < 8; k++) o[k] = acc[k] * r;
        hs[(size_t)v * 16 + sub] = enc8(o);
    }
}

// k_aggL: aggout_bf16[v] = sum_{u->v} hs[u] + hs[v]*deg[v]   (fp8 in, bf16 out for GEMM A)
__global__ __launch_bounds__(256)
void k_aggL(const uint2* __restrict__ hs, const int* __restrict__ row_ptr,
            const int* __restrict__ ssrc, const float* __restrict__ deg,
            bf16* __restrict__ aggout, int n) {
    int v = blockIdx.x * 4 + (threadIdx.x >> 6);
    if (v >= n) return;
    int lane = threadIdx.x & 63;
    int g = lane >> 4, sub = lane & 15;
    int e0 = row_ptr[v], e1 = row_ptr[v + 1];
    uint2 sv = hs[(size_t)v * 16 + sub];   // self row, issued early
    float d = deg[v];
    float acc[8];
#pragma unroll
    for (int k = 0; k < 8; k++) acc[k] = 0.f;
    for (int base = e0; base < e1; base += 16) {
        int mye = base + g * 4;
        int idx[4]; float w[4];
#pragma unroll
        for (int j = 0; j < 4; j++) {
            int e = mye + j;
            w[j] = (e < e1) ? 1.0f : 0.0f;
            idx[j] = ssrc[e < e1 ? e : e1 - 1];
        }
        uint2 x0 = hs[(size_t)idx[0] * 16 + sub];
        uint2 x1 = hs[(size_t)idx[1] * 16 + sub];
        uint2 x2 = hs[(size_t)idx[2] * 16 + sub];
        uint2 x3 = hs[(size_t)idx[3] * 16 + sub];
        float f0[8], f1[8], f2[8], f3[8];
        dec8(x0, f0); dec8(x1, f1); dec8(x2, f2); dec8(x3, f3);
#pragma unroll
        for (int k = 0; k < 8; k++) acc[k] = fmaf(w[0], f0[k], acc[k]);
#pragma unroll
        for (int k = 0; k < 8; k++) acc[k] = fmaf(w[1], f1[k], acc[k]);
#pragma unroll
        for (int k = 0; k < 8; k++) acc[k] = fmaf(w[2], f2[k], acc[k]);
#pragma unroll
        for (int k = 0; k < 8; k++) acc[k] = fmaf(w[3], f3[k], acc[k]);
    }
#pragma unroll
    for (int k = 0; k < 8; k++) acc[k] += __shfl_xor(acc[k], 16);
#pragma unroll
    for (int k = 0; k < 8; k++) acc[k] += __shfl_xor(acc[k], 32);
    if (g == 0) {
        float fs[8];
        dec8(sv, fs);
        bf16x8 wv;
#pragma unroll
        for (int k = 0; k < 8; k++) wv[k] = (bf16)(acc[k] + fs[k] * d);
        *(bf16x8*)(aggout + (size_t)v * H + sub * 8) = wv;
    }
}

// ---------------- GEMM0: h0_fp8[M,128] = A_f32[M,256] @ Wn + bn, fused colsum ----------------

__global__ __launch_bounds__(256)
void k_gemm0(const float* __restrict__ A, const float* __restrict__ Bw,
             const float* __restrict__ bias, uint2* __restrict__ Cg,
             float* __restrict__ colsum, int M) {
    constexpr int K = 256, BM = 64, BN = 128, BK = 64, LDT = BK + 8;
    __shared__ alignas(16) bf16 As[BM][LDT];
    __shared__ alignas(16) bf16 Bs[BN][LDT];
    __shared__ float cs[128];
    const int tid = threadIdx.x;
    const int wave = tid >> 6, lane = tid & 63;
    const int sub = lane & 15, rg = lane >> 4;
    const int blockRow = blockIdx.x * BM;
    if (tid < 128) cs[tid] = 0.f;

    f32x4 acc[8];
#pragma unroll
    for (int t = 0; t < 8; t++) acc[t] = (f32x4){0.f, 0.f, 0.f, 0.f};

    for (int k0 = 0; k0 < K; k0 += BK) {
#pragma unroll
        for (int it = 0; it < 4; it++) {
            int s = it * 256 + tid;
            int row = s >> 4, f4 = (s & 15) * 4;
            int grow = blockRow + row; if (grow > M - 1) grow = M - 1;
            const float4 v = *(const float4*)(A + (size_t)grow * K + k0 + f4);
            bf16x4 w = { (bf16)v.x, (bf16)v.y, (bf16)v.z, (bf16)v.w };
            *(bf16x4*)&As[row][f4] = w;
        }
#pragma unroll
        for (int it = 0; it < 8; it++) {
            int s = it * 256 + tid;
            int kr = s >> 5, f4 = (s & 31) * 4;
            const float4 v = *(const float4*)(Bw + (size_t)(k0 + kr) * BN + f4);
            Bs[f4 + 0][kr] = (bf16)v.x;
            Bs[f4 + 1][kr] = (bf16)v.y;
            Bs[f4 + 2][kr] = (bf16)v.z;
            Bs[f4 + 3][kr] = (bf16)v.w;
        }
        __syncthreads();
#pragma unroll
        for (int kk = 0; kk < BK; kk += 32) {
            bf16x8 af = *(const bf16x8*)&As[wave * 16 + sub][kk + rg * 8];
#pragma unroll
            for (int t = 0; t < 8; t++) {
                bf16x8 bfv = *(const bf16x8*)&Bs[t * 16 + sub][kk + rg * 8];
                acc[t] = __builtin_amdgcn_mfma_f32_16x16x32_bf16(af, bfv, acc[t], 0, 0, 0);
            }
        }
        __syncthreads();
    }
    // epilogue: bias, colsum, restage tile into LDS (Bs reused) for fp8 packing
    bf16* stg = (bf16*)&Bs[0][0];       // viewed as [64][136]
    const int rbase0 = wave * 16 + rg * 4;  // row within tile
    float lsum[8];
#pragma unroll
    for (int t = 0; t < 8; t++) lsum[t] = 0.f;
#pragma unroll
    for (int r = 0; r < 4; r++) {
        int rowt = rbase0 + r;
        if (blockRow + rowt < M) {
#pragma unroll
            for (int t = 0; t < 8; t++) {
                int col = t * 16 + sub;
                float val = acc[t][r] + bias[col];
                lsum[t] += val;
                stg[rowt * 136 + col] = (bf16)val;
            }
        }
    }
#pragma unroll
    for (int t = 0; t < 8; t++) {
        lsum[t] += __shfl_xor(lsum[t], 16);
        lsum[t] += __shfl_xor(lsum[t], 32);
    }
    if (rg == 0) {
#pragma unroll
        for (int t = 0; t < 8; t++) atomicAdd(&cs[t * 16 + sub], lsum[t]);
    }
    __syncthreads();
    if (tid < 128) atomicAdd(&colsum[tid], cs[tid]);
    // pack phase: 64 rows x 16 col-groups of 8
#pragma unroll
    for (int it = 0; it < 4; it++) {
        int s = it * 256 + tid;
        int row = s >> 4, cg = s & 15;
        int grow = blockRow + row;
        if (grow < M) {
            float f[8];
#pragma unroll
            for (int k = 0; k < 8; k++) f[k] = (float)stg[row * 136 + cg * 8 + k];
            Cg[(size_t)grow * 16 + cg] = enc8(f);
        }
    }
}

// ---------------- layer GEMM: leakyrelu(A_bf16[M,128] @ Wgcn + b); writes hs_fp8 = val/deg ----------------

template<bool WRITE_NEXT>
__global__ __launch_bounds__(256)
void k_gemmL(const bf16* __restrict__ A, const float* __restrict__ Bw,
             const float* __restrict__ bias, const float* __restrict__ deg,
             uint2* __restrict__ hs, float* __restrict__ colsum, int M) {
    constexpr int BM = 64, BN = 128, BK = 128, LDT = BK + 8;
    __shared__ alignas(16) bf16 As[BM][LDT];
    __shared__ alignas(16) bf16 Bs[BN][LDT];
    __shared__ float cs[128];
    const int tid = threadIdx.x;
    const int wave = tid >> 6, lane = tid & 63;
    const int sub = lane & 15, rg = lane >> 4;
    const int blockRow = blockIdx.x * BM;
    if (tid < 128) cs[tid] = 0.f;

#pragma unroll
    for (int it = 0; it < 4; it++) {
        int s = it * 256 + tid;
        int row = s >> 4, ch = (s & 15) * 8;
        int grow = blockRow + row; if (grow > M - 1) grow = M - 1;
        bf16x8 v = *(const bf16x8*)(A + (size_t)grow * BK + ch);
        *(bf16x8*)&As[row][ch] = v;
    }
#pragma unroll
    for (int it = 0; it < 16; it++) {
        int s = it * 256 + tid;
        int kr = s >> 5, f4 = (s & 31) * 4;
        const float4 v = *(const float4*)(Bw + (size_t)kr * BN + f4);
        Bs[f4 + 0][kr] = (bf16)v.x;
        Bs[f4 + 1][kr] = (bf16)v.y;
        Bs[f4 + 2][kr] = (bf16)v.z;
        Bs[f4 + 3][kr] = (bf16)v.w;
    }
    __syncthreads();

    f32x4 acc[8];
#pragma unroll
    for (int t = 0; t < 8; t++) acc[t] = (f32x4){0.f, 0.f, 0.f, 0.f};
#pragma unroll
    for (int kk = 0; kk < BK; kk += 32) {
        bf16x8 af = *(const bf16x8*)&As[wave * 16 + sub][kk + rg * 8];
#pragma unroll
        for (int t = 0; t < 8; t++) {
            bf16x8 bfv = *(const bf16x8*)&Bs[t * 16 + sub][kk + rg * 8];
            acc[t] = __builtin_amdgcn_mfma_f32_16x16x32_bf16(af, bfv, acc[t], 0, 0, 0);
        }
    }
    __syncthreads();

    bf16* stg = (bf16*)&Bs[0][0];       // viewed as [64][136]
    const int rbase0 = wave * 16 + rg * 4;
    float lsum[8];
#pragma unroll
    for (int t = 0; t < 8; t++) lsum[t] = 0.f;
#pragma unroll
    for (int r = 0; r < 4; r++) {
        int rowt = rbase0 + r;
        int grow = blockRow + rowt;
        if (grow < M) {
            float rd = WRITE_NEXT ? (1.0f / deg[grow]) : 0.f;
#pragma unroll
            for (int t = 0; t < 8; t++) {
                int col = t * 16 + sub;
                float val = acc[t][r] + bias[col];
                val = (val > 0.f) ? val : NEG * val;
                lsum[t] += val;
                if (WRITE_NEXT) stg[rowt * 136 + col] = (bf16)(val * rd);
            }
        }
    }
#pragma unroll
    for (int t = 0; t < 8; t++) {
        lsum[t] += __shfl_xor(lsum[t], 16);
        lsum[t] += __shfl_xor(lsum[t], 32);
    }
    if (rg == 0) {
#pragma unroll
        for (int t = 0; t < 8; t++) atomicAdd(&cs[t * 16 + sub], lsum[t]);
    }
    __syncthreads();
    if (tid < 128) atomicAdd(&colsum[tid], cs[tid]);
    if (WRITE_NEXT) {
#pragma unroll
        for (int it = 0; it < 4; it++) {
            int s = it * 256 + tid;
            int row = s >> 4, cg = s & 15;
            int grow = blockRow + row;
            if (grow < M) {
                float f[8];
#pragma unroll
                for (int k = 0; k < 8; k++) f[k] = (float)stg[row * 136 + cg * 8 + k];
                hs[(size_t)grow * 16 + cg] = enc8(f);
            }
        }
    }
}

// ---------------- finisher ----------------

__global__ void k_final(const float* __restrict__ colsum, const float* __restrict__ Wpred,
                        const float* __restrict__ bpred, const float* __restrict__ Wcls,
                        const float* __restrict__ bcls, float* __restrict__ out, int n) {
    __shared__ float g[512];
    __shared__ float g2[128];
    __shared__ float lg[2];
    int t = threadIdx.x;  // 128 threads
    float invn = 1.0f / (float)n;
    for (int i = t; i < 512; i += 128) g[i] = colsum[i] * invn;
    __syncthreads();
    float acc = bpred[t];
    for (int i = 0; i < 512; i++) acc += g[i] * Wpred[i * 128 + t];
    g2[t] = acc;
    __syncthreads();
    if (t < 2) {
        float l = bcls[t];
        for (int j = 0; j < 128; j++) l += g2[j] * Wcls[j * 2 + t];
        lg[t] = l;
    }
    __syncthreads();
    if (t == 0) {
        float m = fmaxf(lg[0], lg[1]);
        float e0 = expf(lg[0] - m), e1 = expf(lg[1] - m);
        float s = e0 + e1;
        out[0] = e0 / s;
        out[1] = e1 / s;
    }
}

// ---------------- launch ----------------

extern "C" void kernel_launch(void* const* d_in, const int* in_sizes, int n_in,
                              void* d_out, int out_size, void* d_ws, size_t ws_size,
                              hipStream_t stream) {
    const float* node_feat = (const float*)d_in[0];
    const float* degree = (const float*)d_in[3];
    const float* Wn     = (const float*)d_in[4];
    const float* bn     = (const float*)d_in[5];
    const float* Wgcn   = (const float*)d_in[8];
    const float* bgcn   = (const float*)d_in[9];
    const float* Wpred  = (const float*)d_in[10];
    const float* bpred  = (const float*)d_in[11];
    const float* Wcls   = (const float*)d_in[12];
    const float* bcls   = (const float*)d_in[13];
    const int*   src    = (const int*)d_in[14];
    const int*   dst    = (const int*)d_in[15];
    float* out = (float*)d_out;

    const int N = in_sizes[3];
    const int E = in_sizes[14];
    (void)n_in; (void)out_size; (void)ws_size;

    char* p = (char*)d_ws;
    auto carve = [&](size_t bytes) { char* r = p; p += (bytes + 255) & ~(size_t)255; return r; };
    uint2* h0g    = (uint2*)carve((size_t)N * H);       // fp8 h0 gather table (128 B/row)
    uint2* hsb    = (uint2*)carve((size_t)N * H);       // fp8 pre-scaled hidden gather table
    bf16*  aggb   = (bf16*)carve((size_t)N * H * 2);    // bf16 agg output -> GEMM A
    int*   cnt    = (int*)carve((size_t)N * 4);
    int*   row_ptr= (int*)carve((size_t)(N + 1) * 4);
    int*   nxt    = (int*)carve((size_t)N * 4);
    int*   ssrc   = (int*)carve((size_t)E * 4);
    int*   part   = (int*)carve(256 * 4);
    float* colsum = (float*)carve(512 * 4);

    const int nblk = (N + 255) / 256;
    hipMemsetAsync(cnt, 0, (size_t)N * 4, stream);
    hipMemsetAsync(colsum, 0, 512 * 4, stream);

    k_hist<<<(E + 255) / 256, 256, 0, stream>>>(dst, cnt, E);
    k_scan1<<<nblk, 256, 0, stream>>>(cnt, part, N);
    k_scan2<<<1, 256, 0, stream>>>(part, nblk);
    k_scan3<<<nblk, 256, 0, stream>>>(cnt, part, row_ptr, nxt, N, E);
    k_fill<<<(E + 255) / 256, 256, 0, stream>>>(src, dst, nxt, ssrc, E);

    const int gblk = (N + 63) / 64;
    const int ablk = (N + 3) / 4;

    // h0 = node_feat @ Wn + bn  (fp8 out + colsum[0:128))
    k_gemm0<<<gblk, 256, 0, stream>>>(node_feat, Wn, bn, h0g, colsum, N);
    // fusion: hsb[v] = (sum_{u->v} h0[u]) / deg[v]
    k_agg0<<<ablk, 256, 0, stream>>>(h0g, row_ptr, ssrc, degree, hsb, N);

    // layers: agg (gather + self) -> gemm (leakyrelu, writes next hsb + colsum)
    k_aggL<<<ablk, 256, 0, stream>>>(hsb, row_ptr, ssrc, degree, aggb, N);
    k_gemmL<true><<<gblk, 256, 0, stream>>>(aggb, Wgcn, bgcn, degree, hsb, colsum + 1 * H, N);
    k_aggL<<<ablk, 256, 0, stream>>>(hsb, row_ptr, ssrc, degree, aggb, N);
    k_gemmL<true><<<gblk, 256, 0, stream>>>(aggb, Wgcn, bgcn, degree, hsb, colsum + 2 * H, N);
    k_aggL<<<ablk, 256, 0, stream>>>(hsb, row_ptr, ssrc, degree, aggb, N);
    k_gemmL<false><<<gblk, 256, 0, stream>>>(aggb, Wgcn, bgcn, degree, hsb, colsum + 3 * H, N);

    k_final<<<1, 128, 0, stream>>>(colsum, Wpred, bpred, Wcls, bcls, out, N);
}